// Round 1
// baseline (633.473 us; speedup 1.0000x reference)
//
#include <hip/hip_runtime.h>
#include <hip/hip_fp16.h>

#define E_N 80000
#define T_N 80000

typedef _Float16 h2 __attribute__((ext_vector_type(2)));
typedef _Float16 h4 __attribute__((ext_vector_type(4)));
typedef _Float16 h8 __attribute__((ext_vector_type(8)));
typedef float    f4 __attribute__((ext_vector_type(4)));
typedef float    f2 __attribute__((ext_vector_type(2)));
typedef unsigned int u4 __attribute__((ext_vector_type(4)));

static __device__ __forceinline__ float swishf(float x) {
    return x / (1.0f + __expf(-x));
}

// ---------------------------------------------------------------------------
// KP: pack W_bil[i][j][l] (f32) into f16 MFMA-B-fragment order.
// Wpack group index g = ((j*2 + c)*4 + nt)*64 + lane ; lane holds 8 halves:
//   B[k = quad*8 + u][n = lane&15] = W_bil[i = nt*16 + (lane&15)][j][l = c*32 + quad*8 + u]
// ---------------------------------------------------------------------------
__global__ __launch_bounds__(256) void kp_pack(const float* __restrict__ Wb,
                                               h8* __restrict__ wpack) {
    int g = blockIdx.x * 256 + threadIdx.x;      // 0..32767
    int i    = ((g >> 6) & 3) * 16 + (g & 15);   // nt*16 + (lane&15)
    int c    = (g >> 8) & 1;
    int j    = g >> 9;
    int quad = (g >> 4) & 3;
    int l0   = c * 32 + quad * 8;
    const float* src = Wb + ((i * 64 + j) << 6) + l0;
    h8 v;
#pragma unroll
    for (int u = 0; u < 8; ++u) v[u] = (_Float16)src[u];
    wpack[g] = v;
}

// ---------------------------------------------------------------------------
// K1: xke = f16( swish( (x_kj * rbf) @ W_down ) ), rbf = (rbf0@W_rbf1)@W_rbf2
// Mtile=64, K=256, N=64. fp32 VALU.
// ---------------------------------------------------------------------------
__global__ __launch_bounds__(256) void k1_down(const float* __restrict__ rbf0,
                                               const float* __restrict__ xkj,
                                               const float* __restrict__ W_rbf1,
                                               const float* __restrict__ W_rbf2,
                                               const float* __restrict__ W_down,
                                               _Float16* __restrict__ xke) {
    __shared__ float As[64 * 260];   // stride 260: 2-way LDS aliasing (free)
    int tid = threadIdx.x;
    int row0 = blockIdx.x * 64;

    {   // stage + prescale: 4 threads per row, 64 cols each
        int r = tid >> 2;
        int gr = row0 + r;
        int seg = (tid & 3) * 64;
        float rv[6], r8[8];
#pragma unroll
        for (int q = 0; q < 6; ++q) rv[q] = rbf0[gr * 6 + q];
#pragma unroll
        for (int p = 0; p < 8; ++p) {
            float s = 0.f;
#pragma unroll
            for (int q = 0; q < 6; ++q) s += rv[q] * W_rbf1[q * 8 + p];
            r8[p] = s;
        }
        for (int cc = seg; cc < seg + 64; cc += 4) {
            f4 x4 = *(const f4*)(xkj + (size_t)gr * 256 + cc);
            f4 rb = {0.f, 0.f, 0.f, 0.f};
#pragma unroll
            for (int p = 0; p < 8; ++p)
                rb += r8[p] * *(const f4*)(W_rbf2 + p * 256 + cc);
            *(f4*)&As[r * 260 + cc] = x4 * rb;
        }
    }
    __syncthreads();

    int r0 = (tid >> 4) * 4;
    int c0 = (tid & 15) * 4;
    f4 acc[4] = {};
    for (int k = 0; k < 256; ++k) {
        f4 w4 = *(const f4*)(W_down + (k << 6) + c0);
#pragma unroll
        for (int i2 = 0; i2 < 4; ++i2)
            acc[i2] += As[(r0 + i2) * 260 + k] * w4;
    }
#pragma unroll
    for (int i2 = 0; i2 < 4; ++i2) {
        h4 o;
#pragma unroll
        for (int u = 0; u < 4; ++u) o[u] = (_Float16)swishf(acc[i2][u]);
        *(h4*)(xke + (size_t)(row0 + r0 + i2) * 64 + c0) = o;
    }
}

// ---------------------------------------------------------------------------
// KB1: tt = f16( t @ W_t1 ), Mtile=64, K=294, N=64. fp32 VALU.
// ---------------------------------------------------------------------------
__global__ __launch_bounds__(256) void kb1_tproj(const float* __restrict__ tin,
                                                 const float* __restrict__ W_t1,
                                                 _Float16* __restrict__ ttb) {
    __shared__ float As[64 * 300];   // stride 300: 2-way aliasing (free)
    int tid = threadIdx.x;
    int row0 = blockIdx.x * 64;
    for (int i = tid; i < 64 * 294; i += 256)
        As[(i / 294) * 300 + (i % 294)] = tin[(size_t)row0 * 294 + i];
    __syncthreads();

    int r0 = (tid >> 4) * 4;
    int c0 = (tid & 15) * 4;
    f4 acc[4] = {};
    for (int k = 0; k < 294; ++k) {
        f4 w4 = *(const f4*)(W_t1 + (k << 6) + c0);
#pragma unroll
        for (int i2 = 0; i2 < 4; ++i2)
            acc[i2] += As[(r0 + i2) * 300 + k] * w4;
    }
#pragma unroll
    for (int i2 = 0; i2 < 4; ++i2) {
        h4 o;
#pragma unroll
        for (int u = 0; u < 4; ++u) o[u] = (_Float16)acc[i2][u];
        *(h4*)(ttb + (size_t)(row0 + r0 + i2) * 64 + c0) = o;
    }
}

// ---------------------------------------------------------------------------
// KB2: xkt[w] = xke[idx_kj[w]] * ((sbf@W_sbf1)@W_sbf2)[w]   (f16 out)
// 32 rows/block.
// ---------------------------------------------------------------------------
__global__ __launch_bounds__(256) void kb2_gather(const float* __restrict__ sbf,
                                                  const float* __restrict__ W_sbf1,
                                                  const float* __restrict__ W_sbf2,
                                                  const _Float16* __restrict__ xke,
                                                  const int* __restrict__ idx_kj,
                                                  _Float16* __restrict__ xkt) {
    __shared__ float sbfL[32 * 42];
    __shared__ float midL[32 * 8];
    int tid = threadIdx.x;
    int row0 = blockIdx.x * 32;
    for (int i = tid; i < 32 * 42; i += 256)
        sbfL[i] = sbf[(size_t)row0 * 42 + i];
    __syncthreads();
    {
        int r = tid >> 3, p = tid & 7;
        float m = 0.f;
#pragma unroll
        for (int q = 0; q < 42; ++q) m += sbfL[r * 42 + q] * W_sbf1[q * 8 + p];
        midL[r * 8 + p] = m;
    }
    __syncthreads();
    int r = tid >> 3;
    int c0 = (tid & 7) * 8;
    int w = row0 + r;
    int e = idx_kj[w];
    f4 sa = {}, sb = {};
#pragma unroll
    for (int p = 0; p < 8; ++p) {
        float m = midL[r * 8 + p];
        sa += m * *(const f4*)(W_sbf2 + (p << 6) + c0);
        sb += m * *(const f4*)(W_sbf2 + (p << 6) + c0 + 4);
    }
    h8 xv = *(const h8*)(xke + (size_t)e * 64 + c0);
    h8 o;
#pragma unroll
    for (int u = 0; u < 4; ++u) {
        o[u]     = (_Float16)((float)xv[u]     * sa[u]);
        o[u + 4] = (_Float16)((float)xv[u + 4] * sb[u]);
    }
    *(h8*)(xkt + (size_t)w * 64 + c0) = o;
}

// ---------------------------------------------------------------------------
// KB3: bilinear via on-the-fly outer-product MFMA + atomic scatter to agg.
// Block: 4 waves x 64 rows = 256 rows. Wave: 4 row-tiles x 4 col-tiles (16x16),
// K=4096 split over blockIdx.y (2 x 32 j's).
// ---------------------------------------------------------------------------
__global__ __launch_bounds__(256, 2) void kb3_bilinear(const _Float16* __restrict__ xkt,
                                                       const _Float16* __restrict__ ttp,
                                                       const h8* __restrict__ wpack,
                                                       const int* __restrict__ idx_ji,
                                                       float* __restrict__ agg) {
    __shared__ _Float16 xktL[256 * 72];  // stride 72: aligned + 2-way only
    __shared__ _Float16 ttL[256 * 72];
    int tid = threadIdx.x;
    int lane = tid & 63, wv = tid >> 6;
    int qrow = lane & 15, quad = lane >> 4;
    int row0 = blockIdx.x * 256;
    int jlo = blockIdx.y * 32;

#pragma unroll
    for (int pass = 0; pass < 8; ++pass) {
        int r = pass * 32 + (tid >> 3);
        int part = tid & 7;
        int gr = row0 + r;
        u4 vx = {0, 0, 0, 0}, vt = {0, 0, 0, 0};
        if (gr < T_N) {
            vx = *(const u4*)(xkt + (size_t)gr * 64 + part * 8);
            vt = *(const u4*)(ttp + (size_t)gr * 64 + part * 8);
        }
        *(u4*)&xktL[r * 72 + part * 8] = vx;
        *(u4*)&ttL[r * 72 + part * 8] = vt;
    }
    __syncthreads();

    int wrow = wv * 64;
    h8 xa[4][2];   // lane's xk row-fragment, fixed across all j
#pragma unroll
    for (int rt = 0; rt < 4; ++rt)
#pragma unroll
        for (int c = 0; c < 2; ++c)
            xa[rt][c] = *(const h8*)&xktL[(wrow + rt * 16 + qrow) * 72 + c * 32 + quad * 8];

    f4 acc[4][4] = {};
    for (int j = jlo; j < jlo + 32; ++j) {
        h8 bf[2][4];
#pragma unroll
        for (int c = 0; c < 2; ++c)
#pragma unroll
            for (int nt = 0; nt < 4; ++nt)
                bf[c][nt] = wpack[(((j * 2 + c) * 4 + nt) << 6) + lane];
        _Float16 tv[4];
#pragma unroll
        for (int rt = 0; rt < 4; ++rt)
            tv[rt] = ttL[(wrow + rt * 16 + qrow) * 72 + j];
#pragma unroll
        for (int rt = 0; rt < 4; ++rt) {
            h8 t8 = {tv[rt], tv[rt], tv[rt], tv[rt], tv[rt], tv[rt], tv[rt], tv[rt]};
            h8 a0 = xa[rt][0] * t8;
            h8 a1 = xa[rt][1] * t8;
#pragma unroll
            for (int nt = 0; nt < 4; ++nt) {
                acc[rt][nt] = __builtin_amdgcn_mfma_f32_16x16x32_f16(a0, bf[0][nt], acc[rt][nt], 0, 0, 0);
                acc[rt][nt] = __builtin_amdgcn_mfma_f32_16x16x32_f16(a1, bf[1][nt], acc[rt][nt], 0, 0, 0);
            }
        }
    }

    // C/D layout: col = lane&15, row = quad*4 + reg  (verified m89/m91)
#pragma unroll
    for (int rt = 0; rt < 4; ++rt) {
#pragma unroll
        for (int rr = 0; rr < 4; ++rr) {
            int w = row0 + wrow + rt * 16 + quad * 4 + rr;
            if (w < T_N) {
                int e = idx_ji[w];
                float* dst = agg + (size_t)e * 64 + qrow;
#pragma unroll
                for (int nt = 0; nt < 4; ++nt)
                    atomicAdd(dst + nt * 16, acc[rt][nt][rr]);
            }
        }
    }
}

// ---------------------------------------------------------------------------
// K4: out = swish( agg @ W_up ), Mtile=32, K=64, N=256. fp32 VALU.
// ---------------------------------------------------------------------------
__global__ __launch_bounds__(256) void k4_up(const float* __restrict__ agg,
                                             const float* __restrict__ W_up,
                                             float* __restrict__ out) {
    __shared__ float aggL[32 * 66];  // stride 66: conflict-free
    int tid = threadIdx.x;
    int row0 = blockIdx.x * 32;
    for (int i = tid; i < 1024; i += 256) {   // float2 units
        int r = i >> 5, c2 = i & 31;
        *(f2*)&aggL[r * 66 + c2 * 2] = *(const f2*)(agg + (size_t)(row0 + r) * 64 + c2 * 2);
    }
    __syncthreads();

    int r0 = (tid >> 5) * 4;
    int c0 = (tid & 31) * 8;
    f4 acc[4][2] = {};
    for (int k = 0; k < 64; ++k) {
        f4 wa = *(const f4*)(W_up + (k << 8) + c0);
        f4 wb = *(const f4*)(W_up + (k << 8) + c0 + 4);
#pragma unroll
        for (int i2 = 0; i2 < 4; ++i2) {
            float a = aggL[(r0 + i2) * 66 + k];
            acc[i2][0] += a * wa;
            acc[i2][1] += a * wb;
        }
    }
#pragma unroll
    for (int i2 = 0; i2 < 4; ++i2) {
        f4 oa, ob;
#pragma unroll
        for (int u = 0; u < 4; ++u) {
            oa[u] = swishf(acc[i2][0][u]);
            ob[u] = swishf(acc[i2][1][u]);
        }
        float* dst = out + (size_t)(row0 + r0 + i2) * 256 + c0;
        *(f4*)dst = oa;
        *(f4*)(dst + 4) = ob;
    }
}

// ---------------------------------------------------------------------------
extern "C" void kernel_launch(void* const* d_in, const int* in_sizes, int n_in,
                              void* d_out, int out_size, void* d_ws, size_t ws_size,
                              hipStream_t stream) {
    const float* rbf0   = (const float*)d_in[1];
    const float* sbf    = (const float*)d_in[2];
    const float* tin    = (const float*)d_in[3];
    const float* xkj    = (const float*)d_in[4];
    const int*   idx_kj = (const int*)d_in[6];
    const int*   idx_ji = (const int*)d_in[7];
    const float* W_rbf1 = (const float*)d_in[8];
    const float* W_rbf2 = (const float*)d_in[9];
    const float* W_sbf1 = (const float*)d_in[10];
    const float* W_sbf2 = (const float*)d_in[11];
    const float* W_t1   = (const float*)d_in[12];
    const float* W_down = (const float*)d_in[13];
    const float* W_up   = (const float*)d_in[14];
    const float* W_bil  = (const float*)d_in[15];

    // workspace: xke (10.24MB) | agg (20.48MB) | wpack (0.5MB)  = ~31.3MB
    char* ws = (char*)d_ws;
    _Float16* xke = (_Float16*)ws;
    float*    agg = (float*)(ws + 10240000);
    h8*     wpack = (h8*)(ws + 30720000);
    // tt/xkt live in d_out's first 20.5MB (dead before k4_up writes out)
    _Float16* ttb = (_Float16*)d_out;
    _Float16* xkt = (_Float16*)((char*)d_out + 10240000);
    float*    out = (float*)d_out;

    kp_pack<<<128, 256, 0, stream>>>(W_bil, wpack);
    k1_down<<<1250, 256, 0, stream>>>(rbf0, xkj, W_rbf1, W_rbf2, W_down, xke);
    kb1_tproj<<<1250, 256, 0, stream>>>(tin, W_t1, ttb);
    kb2_gather<<<2500, 256, 0, stream>>>(sbf, W_sbf1, W_sbf2, xke, idx_kj, xkt);
    hipMemsetAsync(agg, 0, (size_t)E_N * 64 * 4, stream);
    kb3_bilinear<<<dim3(313, 2), 256, 0, stream>>>(xkt, ttb, wpack, idx_ji, agg);
    k4_up<<<2500, 256, 0, stream>>>(agg, W_up, out);
}

// Round 2
// 479.766 us; speedup vs baseline: 1.3204x; 1.3204x over previous
//
#include <hip/hip_runtime.h>
#include <hip/hip_fp16.h>

#define E_N 80000
#define T_N 80000

typedef _Float16 h4 __attribute__((ext_vector_type(4)));
typedef _Float16 h8 __attribute__((ext_vector_type(8)));
typedef float    f4 __attribute__((ext_vector_type(4)));
typedef float    f2 __attribute__((ext_vector_type(2)));
typedef unsigned int u4 __attribute__((ext_vector_type(4)));

static __device__ __forceinline__ float swishf(float x) {
    return x / (1.0f + __expf(-x));
}

// ---------------------------------------------------------------------------
// KP: pack W_bil[i][j][l] (f32) into f16 MFMA-B-fragment order (validated R1).
// ---------------------------------------------------------------------------
__global__ __launch_bounds__(256) void kp_pack(const float* __restrict__ Wb,
                                               h8* __restrict__ wpack) {
    int g = blockIdx.x * 256 + threadIdx.x;      // 0..32767
    int i    = ((g >> 6) & 3) * 16 + (g & 15);
    int c    = (g >> 8) & 1;
    int j    = g >> 9;
    int quad = (g >> 4) & 3;
    int l0   = c * 32 + quad * 8;
    const float* src = Wb + ((i * 64 + j) << 6) + l0;
    h8 v;
#pragma unroll
    for (int u = 0; u < 8; ++u) v[u] = (_Float16)src[u];
    wpack[g] = v;
}

// ---------------------------------------------------------------------------
// KPW: generic pack of W[K,N] (y = x@W) into f16 B-frag layout.
// frag f = kt*NT + nt ; lane holds B[k = kt*32 + quad*8 + u][n = nt*16 + m].
// k >= Ksrc zero-padded.
// ---------------------------------------------------------------------------
__global__ __launch_bounds__(256) void kpack_w(const float* __restrict__ src,
                                               h8* __restrict__ dst,
                                               int Ksrc, int N, int NT) {
    int g = blockIdx.x * 256 + threadIdx.x;
    int lane = g & 63, frag = g >> 6;
    int nt = frag % NT, kt = frag / NT;
    int quad = (lane >> 4);
    int n = nt * 16 + (lane & 15);
    int k0 = kt * 32 + quad * 8;
    h8 v;
#pragma unroll
    for (int u = 0; u < 8; ++u) {
        int k = k0 + u;
        v[u] = (k < Ksrc) ? (_Float16)src[(size_t)k * N + n] : (_Float16)0.0f;
    }
    dst[g] = v;
}

// ---------------------------------------------------------------------------
// K1 (MFMA): xke = f16( swish( (x_kj * rbf) @ W_down ) )
// rbf = (rbf0@W_rbf1)@W_rbf2 expanded per-lane. No LDS; direct A-frag gen.
// Block 4 waves x 32 rows = 128 rows. K=256 (8 k-tiles), N=64 (4 n-tiles).
// ---------------------------------------------------------------------------
__global__ __launch_bounds__(256) void k1_down(const float* __restrict__ rbf0,
                                               const float* __restrict__ xkj,
                                               const float* __restrict__ W_rbf1,
                                               const float* __restrict__ W_rbf2,
                                               const h8* __restrict__ wpd,
                                               _Float16* __restrict__ xke) {
    int tid = threadIdx.x;
    int lane = tid & 63, wv = tid >> 6;
    int m = lane & 15, quad = lane >> 4;
    int rowb = blockIdx.x * 128 + wv * 32;

    float r8[2][8];
#pragma unroll
    for (int rt = 0; rt < 2; ++rt) {
        int r = rowb + rt * 16 + m;
        float rv[6];
#pragma unroll
        for (int q = 0; q < 6; ++q) rv[q] = rbf0[(size_t)r * 6 + q];
#pragma unroll
        for (int p = 0; p < 8; ++p) {
            float s = 0.f;
#pragma unroll
            for (int q = 0; q < 6; ++q) s += rv[q] * W_rbf1[q * 8 + p];
            r8[rt][p] = s;
        }
    }

    f4 acc[2][4] = {};
    for (int kb = 0; kb < 4; ++kb) {
#pragma unroll
        for (int kt = 0; kt < 2; ++kt) {
            int k0 = kb * 64 + kt * 32 + quad * 8;
            f4 w2lo[8], w2hi[8];
#pragma unroll
            for (int p = 0; p < 8; ++p) {
                w2lo[p] = *(const f4*)(W_rbf2 + p * 256 + k0);
                w2hi[p] = *(const f4*)(W_rbf2 + p * 256 + k0 + 4);
            }
            h8 afrag[2];
#pragma unroll
            for (int rt = 0; rt < 2; ++rt) {
                size_t base = (size_t)(rowb + rt * 16 + m) * 256 + k0;
                f4 xlo = *(const f4*)(xkj + base);
                f4 xhi = *(const f4*)(xkj + base + 4);
                f4 rlo = {}, rhi = {};
#pragma unroll
                for (int p = 0; p < 8; ++p) {
                    rlo += r8[rt][p] * w2lo[p];
                    rhi += r8[rt][p] * w2hi[p];
                }
                rlo *= xlo; rhi *= xhi;
                h8 a;
#pragma unroll
                for (int u = 0; u < 4; ++u) {
                    a[u]     = (_Float16)rlo[u];
                    a[u + 4] = (_Float16)rhi[u];
                }
                afrag[rt] = a;
            }
#pragma unroll
            for (int nt = 0; nt < 4; ++nt) {
                h8 b = wpd[(((kb * 2 + kt) * 4 + nt) << 6) + lane];
#pragma unroll
                for (int rt = 0; rt < 2; ++rt)
                    acc[rt][nt] = __builtin_amdgcn_mfma_f32_16x16x32_f16(afrag[rt], b, acc[rt][nt], 0, 0, 0);
            }
        }
    }

    // C/D: col = m (n within tile), row = quad*4 + rr
#pragma unroll
    for (int rt = 0; rt < 2; ++rt)
#pragma unroll
        for (int nt = 0; nt < 4; ++nt)
#pragma unroll
            for (int rr = 0; rr < 4; ++rr) {
                int row = rowb + rt * 16 + quad * 4 + rr;
                xke[(size_t)row * 64 + nt * 16 + m] = (_Float16)swishf(acc[rt][nt][rr]);
            }
}

// ---------------------------------------------------------------------------
// KB1 (MFMA): tt = f16( t @ W_t1 ). K=294 padded to 320 (10 k-tiles), N=64.
// Block 4 waves x 32 rows = 128 rows. No LDS.
// ---------------------------------------------------------------------------
__global__ __launch_bounds__(256) void kb1_tproj(const float* __restrict__ tin,
                                                 const h8* __restrict__ wpt,
                                                 _Float16* __restrict__ ttb) {
    int tid = threadIdx.x;
    int lane = tid & 63, wv = tid >> 6;
    int m = lane & 15, quad = lane >> 4;
    int rowb = blockIdx.x * 128 + wv * 32;

    f4 acc[2][4] = {};
    for (int ktg = 0; ktg < 10; ++ktg) {
        int k0 = ktg * 32 + quad * 8;
        h8 afrag[2];
#pragma unroll
        for (int rt = 0; rt < 2; ++rt) {
            size_t base = (size_t)(rowb + rt * 16 + m) * 294 + k0;
            h8 a;
            if (k0 + 8 <= 294) {
                f2 t0 = *(const f2*)(tin + base);
                f2 t1 = *(const f2*)(tin + base + 2);
                f2 t2 = *(const f2*)(tin + base + 4);
                f2 t3 = *(const f2*)(tin + base + 6);
                a[0] = (_Float16)t0[0]; a[1] = (_Float16)t0[1];
                a[2] = (_Float16)t1[0]; a[3] = (_Float16)t1[1];
                a[4] = (_Float16)t2[0]; a[5] = (_Float16)t2[1];
                a[6] = (_Float16)t3[0]; a[7] = (_Float16)t3[1];
            } else {
#pragma unroll
                for (int u = 0; u < 8; ++u) {
                    int k = k0 + u;
                    a[u] = (k < 294) ? (_Float16)tin[base + u] : (_Float16)0.0f;
                }
            }
            afrag[rt] = a;
        }
#pragma unroll
        for (int nt = 0; nt < 4; ++nt) {
            h8 b = wpt[((ktg * 4 + nt) << 6) + lane];
#pragma unroll
            for (int rt = 0; rt < 2; ++rt)
                acc[rt][nt] = __builtin_amdgcn_mfma_f32_16x16x32_f16(afrag[rt], b, acc[rt][nt], 0, 0, 0);
        }
    }

#pragma unroll
    for (int rt = 0; rt < 2; ++rt)
#pragma unroll
        for (int nt = 0; nt < 4; ++nt)
#pragma unroll
            for (int rr = 0; rr < 4; ++rr) {
                int row = rowb + rt * 16 + quad * 4 + rr;
                ttb[(size_t)row * 64 + nt * 16 + m] = (_Float16)acc[rt][nt][rr];
            }
}

// ---------------------------------------------------------------------------
// KB2: xkt[w] = xke[idx_kj[w]] * ((sbf@W_sbf1)@W_sbf2)[w]   (f16 out)
// ---------------------------------------------------------------------------
__global__ __launch_bounds__(256) void kb2_gather(const float* __restrict__ sbf,
                                                  const float* __restrict__ W_sbf1,
                                                  const float* __restrict__ W_sbf2,
                                                  const _Float16* __restrict__ xke,
                                                  const int* __restrict__ idx_kj,
                                                  _Float16* __restrict__ xkt) {
    __shared__ float sbfL[32 * 42];
    __shared__ float midL[32 * 8];
    int tid = threadIdx.x;
    int row0 = blockIdx.x * 32;
    for (int i = tid; i < 32 * 42; i += 256)
        sbfL[i] = sbf[(size_t)row0 * 42 + i];
    __syncthreads();
    {
        int r = tid >> 3, p = tid & 7;
        float mm = 0.f;
#pragma unroll
        for (int q = 0; q < 42; ++q) mm += sbfL[r * 42 + q] * W_sbf1[q * 8 + p];
        midL[r * 8 + p] = mm;
    }
    __syncthreads();
    int r = tid >> 3;
    int c0 = (tid & 7) * 8;
    int w = row0 + r;
    int e = idx_kj[w];
    f4 sa = {}, sb = {};
#pragma unroll
    for (int p = 0; p < 8; ++p) {
        float mm = midL[r * 8 + p];
        sa += mm * *(const f4*)(W_sbf2 + (p << 6) + c0);
        sb += mm * *(const f4*)(W_sbf2 + (p << 6) + c0 + 4);
    }
    h8 xv = *(const h8*)(xke + (size_t)e * 64 + c0);
    h8 o;
#pragma unroll
    for (int u = 0; u < 4; ++u) {
        o[u]     = (_Float16)((float)xv[u]     * sa[u]);
        o[u + 4] = (_Float16)((float)xv[u + 4] * sb[u]);
    }
    *(h8*)(xkt + (size_t)w * 64 + c0) = o;
}

// ---------------------------------------------------------------------------
// KB3: bilinear via on-the-fly outer-product MFMA + atomic scatter (R1-pass).
// ---------------------------------------------------------------------------
__global__ __launch_bounds__(256, 2) void kb3_bilinear(const _Float16* __restrict__ xkt,
                                                       const _Float16* __restrict__ ttp,
                                                       const h8* __restrict__ wpack,
                                                       const int* __restrict__ idx_ji,
                                                       float* __restrict__ agg) {
    __shared__ _Float16 xktL[256 * 72];
    __shared__ _Float16 ttL[256 * 72];
    int tid = threadIdx.x;
    int lane = tid & 63, wv = tid >> 6;
    int qrow = lane & 15, quad = lane >> 4;
    int row0 = blockIdx.x * 256;
    int jlo = blockIdx.y * 32;

#pragma unroll
    for (int pass = 0; pass < 8; ++pass) {
        int r = pass * 32 + (tid >> 3);
        int part = tid & 7;
        int gr = row0 + r;
        u4 vx = {0, 0, 0, 0}, vt = {0, 0, 0, 0};
        if (gr < T_N) {
            vx = *(const u4*)(xkt + (size_t)gr * 64 + part * 8);
            vt = *(const u4*)(ttp + (size_t)gr * 64 + part * 8);
        }
        *(u4*)&xktL[r * 72 + part * 8] = vx;
        *(u4*)&ttL[r * 72 + part * 8] = vt;
    }
    __syncthreads();

    int wrow = wv * 64;
    h8 xa[4][2];
#pragma unroll
    for (int rt = 0; rt < 4; ++rt)
#pragma unroll
        for (int c = 0; c < 2; ++c)
            xa[rt][c] = *(const h8*)&xktL[(wrow + rt * 16 + qrow) * 72 + c * 32 + quad * 8];

    f4 acc[4][4] = {};
    for (int j = jlo; j < jlo + 32; ++j) {
        h8 bf[2][4];
#pragma unroll
        for (int c = 0; c < 2; ++c)
#pragma unroll
            for (int nt = 0; nt < 4; ++nt)
                bf[c][nt] = wpack[(((j * 2 + c) * 4 + nt) << 6) + lane];
        _Float16 tv[4];
#pragma unroll
        for (int rt = 0; rt < 4; ++rt)
            tv[rt] = ttL[(wrow + rt * 16 + qrow) * 72 + j];
#pragma unroll
        for (int rt = 0; rt < 4; ++rt) {
            h8 t8 = {tv[rt], tv[rt], tv[rt], tv[rt], tv[rt], tv[rt], tv[rt], tv[rt]};
            h8 a0 = xa[rt][0] * t8;
            h8 a1 = xa[rt][1] * t8;
#pragma unroll
            for (int nt = 0; nt < 4; ++nt) {
                acc[rt][nt] = __builtin_amdgcn_mfma_f32_16x16x32_f16(a0, bf[0][nt], acc[rt][nt], 0, 0, 0);
                acc[rt][nt] = __builtin_amdgcn_mfma_f32_16x16x32_f16(a1, bf[1][nt], acc[rt][nt], 0, 0, 0);
            }
        }
    }

#pragma unroll
    for (int rt = 0; rt < 4; ++rt) {
#pragma unroll
        for (int rr = 0; rr < 4; ++rr) {
            int w = row0 + wrow + rt * 16 + quad * 4 + rr;
            if (w < T_N) {
                int e = idx_ji[w];
                float* dst = agg + (size_t)e * 64 + qrow;
#pragma unroll
                for (int nt = 0; nt < 4; ++nt)
                    atomicAdd(dst + nt * 16, acc[rt][nt][rr]);
            }
        }
    }
}

// ---------------------------------------------------------------------------
// K4 (MFMA): out = swish( agg @ W_up ). K=64 (2 kt), N=256 (16 nt).
// Block 4 waves x 16 rows = 64 rows. No LDS.
// ---------------------------------------------------------------------------
__global__ __launch_bounds__(256) void k4_up(const float* __restrict__ agg,
                                             const h8* __restrict__ wpu,
                                             float* __restrict__ out) {
    int tid = threadIdx.x;
    int lane = tid & 63, wv = tid >> 6;
    int m = lane & 15, quad = lane >> 4;
    int rowb = blockIdx.x * 64 + wv * 16;

    f4 acc[16] = {};
#pragma unroll
    for (int kt = 0; kt < 2; ++kt) {
        const float* ap = agg + (size_t)(rowb + m) * 64 + kt * 32 + quad * 8;
        f4 alo = *(const f4*)ap;
        f4 ahi = *(const f4*)(ap + 4);
        h8 a;
#pragma unroll
        for (int u = 0; u < 4; ++u) {
            a[u]     = (_Float16)alo[u];
            a[u + 4] = (_Float16)ahi[u];
        }
#pragma unroll
        for (int nt = 0; nt < 16; ++nt) {
            h8 b = wpu[((kt * 16 + nt) << 6) + lane];
            acc[nt] = __builtin_amdgcn_mfma_f32_16x16x32_f16(a, b, acc[nt], 0, 0, 0);
        }
    }

#pragma unroll
    for (int nt = 0; nt < 16; ++nt)
#pragma unroll
        for (int rr = 0; rr < 4; ++rr) {
            int row = rowb + quad * 4 + rr;
            out[(size_t)row * 256 + nt * 16 + m] = swishf(acc[nt][rr]);
        }
}

// ---------------------------------------------------------------------------
extern "C" void kernel_launch(void* const* d_in, const int* in_sizes, int n_in,
                              void* d_out, int out_size, void* d_ws, size_t ws_size,
                              hipStream_t stream) {
    const float* rbf0   = (const float*)d_in[1];
    const float* sbf    = (const float*)d_in[2];
    const float* tin    = (const float*)d_in[3];
    const float* xkj    = (const float*)d_in[4];
    const int*   idx_kj = (const int*)d_in[6];
    const int*   idx_ji = (const int*)d_in[7];
    const float* W_rbf1 = (const float*)d_in[8];
    const float* W_rbf2 = (const float*)d_in[9];
    const float* W_sbf1 = (const float*)d_in[10];
    const float* W_sbf2 = (const float*)d_in[11];
    const float* W_t1   = (const float*)d_in[12];
    const float* W_down = (const float*)d_in[13];
    const float* W_up   = (const float*)d_in[14];
    const float* W_bil  = (const float*)d_in[15];

    // ws: xke 10.24MB | agg 20.48MB | wpack_bil 512KB | wpd 32KB | wpt 40KB | wpu 32KB
    char* ws = (char*)d_ws;
    _Float16* xke = (_Float16*)ws;
    float*    agg = (float*)(ws + 10240000);
    h8* wpack_bil = (h8*)(ws + 30720000);
    h8* wpd       = (h8*)(ws + 31244288);
    h8* wpt       = (h8*)(ws + 31277056);
    h8* wpu       = (h8*)(ws + 31318016);
    // tt/xkt live in d_out's first 20.5MB (dead before k4_up writes out)
    _Float16* ttb = (_Float16*)d_out;
    _Float16* xkt = (_Float16*)((char*)d_out + 10240000);
    float*    out = (float*)d_out;

    kp_pack<<<128, 256, 0, stream>>>(W_bil, wpack_bil);
    kpack_w<<<8,  256, 0, stream>>>(W_down, wpd, 256, 64, 4);
    kpack_w<<<10, 256, 0, stream>>>(W_t1,   wpt, 294, 64, 4);
    kpack_w<<<8,  256, 0, stream>>>(W_up,   wpu, 64, 256, 16);
    k1_down<<<625, 256, 0, stream>>>(rbf0, xkj, W_rbf1, W_rbf2, wpd, xke);
    kb1_tproj<<<625, 256, 0, stream>>>(tin, wpt, ttb);
    kb2_gather<<<2500, 256, 0, stream>>>(sbf, W_sbf1, W_sbf2, xke, idx_kj, xkt);
    hipMemsetAsync(agg, 0, (size_t)E_N * 64 * 4, stream);
    kb3_bilinear<<<dim3(313, 2), 256, 0, stream>>>(xkt, ttb, wpack_bil, idx_ji, agg);
    k4_up<<<1250, 256, 0, stream>>>(agg, wpu, out);
}

// Round 3
// 475.790 us; speedup vs baseline: 1.3314x; 1.0084x over previous
//
#include <hip/hip_runtime.h>
#include <hip/hip_fp16.h>

#define E_N 80000
#define T_N 80000

typedef _Float16 h4 __attribute__((ext_vector_type(4)));
typedef _Float16 h8 __attribute__((ext_vector_type(8)));
typedef float    f4 __attribute__((ext_vector_type(4)));
typedef float    f2 __attribute__((ext_vector_type(2)));
typedef unsigned int u4 __attribute__((ext_vector_type(4)));

static __device__ __forceinline__ float swishf(float x) {
    return x / (1.0f + __expf(-x));
}

// ---------------------------------------------------------------------------
// Fused weight packing (one launch instead of four).
// kp_pack body (W_bil, validated R1) : blocks [0,128)
// kpack_w (W_down 256x64, NT=4)      : blocks [128,136)
// kpack_w (W_t1   294x64, NT=4, pad) : blocks [136,146)
// kpack_w (W_up    64x256, NT=16)    : blocks [146,154)
// ---------------------------------------------------------------------------
static __device__ __forceinline__ void pack_w_dev(const float* __restrict__ src,
                                                  h8* __restrict__ dst,
                                                  int g, int Ksrc, int N, int NT) {
    int lane = g & 63, frag = g >> 6;
    int nt = frag % NT, kt = frag / NT;
    int quad = (lane >> 4);
    int n = nt * 16 + (lane & 15);
    int k0 = kt * 32 + quad * 8;
    h8 v;
#pragma unroll
    for (int u = 0; u < 8; ++u) {
        int k = k0 + u;
        v[u] = (k < Ksrc) ? (_Float16)src[(size_t)k * N + n] : (_Float16)0.0f;
    }
    dst[g] = v;
}

__global__ __launch_bounds__(256) void kpack_all(const float* __restrict__ Wb,  h8* __restrict__ wbil,
                                                 const float* __restrict__ Wd,  h8* __restrict__ wpd,
                                                 const float* __restrict__ Wt,  h8* __restrict__ wpt,
                                                 const float* __restrict__ Wu,  h8* __restrict__ wpu) {
    int b = blockIdx.x, tid = threadIdx.x;
    if (b < 128) {
        int g = b * 256 + tid;                      // 0..32767
        int i    = ((g >> 6) & 3) * 16 + (g & 15);
        int c    = (g >> 8) & 1;
        int j    = g >> 9;
        int quad = (g >> 4) & 3;
        int l0   = c * 32 + quad * 8;
        const float* src = Wb + ((i * 64 + j) << 6) + l0;
        h8 v;
#pragma unroll
        for (int u = 0; u < 8; ++u) v[u] = (_Float16)src[u];
        wbil[g] = v;
    } else if (b < 136) {
        pack_w_dev(Wd, wpd, (b - 128) * 256 + tid, 256, 64, 4);
    } else if (b < 146) {
        pack_w_dev(Wt, wpt, (b - 136) * 256 + tid, 294, 64, 4);
    } else {
        pack_w_dev(Wu, wpu, (b - 146) * 256 + tid, 64, 256, 16);
    }
}

// ---------------------------------------------------------------------------
// K1 (MFMA): xke = f16( swish( (x_kj * rbf) @ W_down ) )
// rbf = (rbf0@W_rbf1)@W_rbf2 expanded per-lane from registers; incremental
// W_rbf2 accumulation (no 64-reg array -> higher occupancy).
// Block 4 waves x 32 rows = 128 rows. 8 k-tiles of 32, N=64 (4 n-tiles).
// ---------------------------------------------------------------------------
__global__ __launch_bounds__(256, 4) void k1_down(const float* __restrict__ rbf0,
                                                  const float* __restrict__ xkj,
                                                  const float* __restrict__ W_rbf1,
                                                  const float* __restrict__ W_rbf2,
                                                  const h8* __restrict__ wpd,
                                                  _Float16* __restrict__ xke) {
    int tid = threadIdx.x;
    int lane = tid & 63, wv = tid >> 6;
    int m = lane & 15, quad = lane >> 4;
    int rowb = blockIdx.x * 128 + wv * 32;

    float r8[2][8];
#pragma unroll
    for (int rt = 0; rt < 2; ++rt) {
        int r = rowb + rt * 16 + m;
        float rv[6];
#pragma unroll
        for (int q = 0; q < 6; ++q) rv[q] = rbf0[(size_t)r * 6 + q];
#pragma unroll
        for (int p = 0; p < 8; ++p) {
            float s = 0.f;
#pragma unroll
            for (int q = 0; q < 6; ++q) s += rv[q] * W_rbf1[q * 8 + p];
            r8[rt][p] = s;
        }
    }

    f4 acc[2][4] = {};
#pragma unroll
    for (int kb = 0; kb < 8; ++kb) {
        int k0 = kb * 32 + quad * 8;
        h8 afrag[2];
#pragma unroll
        for (int rt = 0; rt < 2; ++rt) {
            f4 rlo = {}, rhi = {};
#pragma unroll
            for (int p = 0; p < 8; ++p) {
                rlo += r8[rt][p] * *(const f4*)(W_rbf2 + p * 256 + k0);
                rhi += r8[rt][p] * *(const f4*)(W_rbf2 + p * 256 + k0 + 4);
            }
            size_t base = (size_t)(rowb + rt * 16 + m) * 256 + k0;
            f4 xlo = *(const f4*)(xkj + base);
            f4 xhi = *(const f4*)(xkj + base + 4);
            rlo *= xlo; rhi *= xhi;
            h8 a;
#pragma unroll
            for (int u = 0; u < 4; ++u) {
                a[u]     = (_Float16)rlo[u];
                a[u + 4] = (_Float16)rhi[u];
            }
            afrag[rt] = a;
        }
#pragma unroll
        for (int nt = 0; nt < 4; ++nt) {
            h8 b = wpd[((kb * 4 + nt) << 6) + lane];
            acc[0][nt] = __builtin_amdgcn_mfma_f32_16x16x32_f16(afrag[0], b, acc[0][nt], 0, 0, 0);
            acc[1][nt] = __builtin_amdgcn_mfma_f32_16x16x32_f16(afrag[1], b, acc[1][nt], 0, 0, 0);
        }
    }

#pragma unroll
    for (int rt = 0; rt < 2; ++rt)
#pragma unroll
        for (int nt = 0; nt < 4; ++nt)
#pragma unroll
            for (int rr = 0; rr < 4; ++rr) {
                int row = rowb + rt * 16 + quad * 4 + rr;
                xke[(size_t)row * 64 + nt * 16 + m] = (_Float16)swishf(acc[rt][nt][rr]);
            }
}

// ---------------------------------------------------------------------------
// KB1 (MFMA): tt = f16( t @ W_t1 ). K=294 padded to 320 (10 k-tiles), N=64.
// ---------------------------------------------------------------------------
__global__ __launch_bounds__(256) void kb1_tproj(const float* __restrict__ tin,
                                                 const h8* __restrict__ wpt,
                                                 _Float16* __restrict__ ttb) {
    int tid = threadIdx.x;
    int lane = tid & 63, wv = tid >> 6;
    int m = lane & 15, quad = lane >> 4;
    int rowb = blockIdx.x * 128 + wv * 32;

    f4 acc[2][4] = {};
    for (int ktg = 0; ktg < 10; ++ktg) {
        int k0 = ktg * 32 + quad * 8;
        h8 afrag[2];
#pragma unroll
        for (int rt = 0; rt < 2; ++rt) {
            size_t base = (size_t)(rowb + rt * 16 + m) * 294 + k0;
            h8 a;
            if (k0 + 8 <= 294) {
                f2 t0 = *(const f2*)(tin + base);
                f2 t1 = *(const f2*)(tin + base + 2);
                f2 t2 = *(const f2*)(tin + base + 4);
                f2 t3 = *(const f2*)(tin + base + 6);
                a[0] = (_Float16)t0[0]; a[1] = (_Float16)t0[1];
                a[2] = (_Float16)t1[0]; a[3] = (_Float16)t1[1];
                a[4] = (_Float16)t2[0]; a[5] = (_Float16)t2[1];
                a[6] = (_Float16)t3[0]; a[7] = (_Float16)t3[1];
            } else {
#pragma unroll
                for (int u = 0; u < 8; ++u) {
                    int k = k0 + u;
                    a[u] = (k < 294) ? (_Float16)tin[base + u] : (_Float16)0.0f;
                }
            }
            afrag[rt] = a;
        }
#pragma unroll
        for (int nt = 0; nt < 4; ++nt) {
            h8 b = wpt[((ktg * 4 + nt) << 6) + lane];
#pragma unroll
            for (int rt = 0; rt < 2; ++rt)
                acc[rt][nt] = __builtin_amdgcn_mfma_f32_16x16x32_f16(afrag[rt], b, acc[rt][nt], 0, 0, 0);
        }
    }

#pragma unroll
    for (int rt = 0; rt < 2; ++rt)
#pragma unroll
        for (int nt = 0; nt < 4; ++nt)
#pragma unroll
            for (int rr = 0; rr < 4; ++rr) {
                int row = rowb + rt * 16 + quad * 4 + rr;
                ttb[(size_t)row * 64 + nt * 16 + m] = (_Float16)acc[rt][nt][rr];
            }
}

// ---------------------------------------------------------------------------
// KB2: xkt[w] = xke[idx_kj[w]] * ((sbf@W_sbf1)@W_sbf2)[w]   (f16 out)
// ---------------------------------------------------------------------------
__global__ __launch_bounds__(256) void kb2_gather(const float* __restrict__ sbf,
                                                  const float* __restrict__ W_sbf1,
                                                  const float* __restrict__ W_sbf2,
                                                  const _Float16* __restrict__ xke,
                                                  const int* __restrict__ idx_kj,
                                                  _Float16* __restrict__ xkt) {
    __shared__ float sbfL[32 * 42];
    __shared__ float midL[32 * 8];
    int tid = threadIdx.x;
    int row0 = blockIdx.x * 32;
    for (int i = tid; i < 32 * 42; i += 256)
        sbfL[i] = sbf[(size_t)row0 * 42 + i];
    __syncthreads();
    {
        int r = tid >> 3, p = tid & 7;
        float mm = 0.f;
#pragma unroll
        for (int q = 0; q < 42; ++q) mm += sbfL[r * 42 + q] * W_sbf1[q * 8 + p];
        midL[r * 8 + p] = mm;
    }
    __syncthreads();
    int r = tid >> 3;
    int c0 = (tid & 7) * 8;
    int w = row0 + r;
    int e = idx_kj[w];
    f4 sa = {}, sb = {};
#pragma unroll
    for (int p = 0; p < 8; ++p) {
        float mm = midL[r * 8 + p];
        sa += mm * *(const f4*)(W_sbf2 + (p << 6) + c0);
        sb += mm * *(const f4*)(W_sbf2 + (p << 6) + c0 + 4);
    }
    h8 xv = *(const h8*)(xke + (size_t)e * 64 + c0);
    h8 o;
#pragma unroll
    for (int u = 0; u < 4; ++u) {
        o[u]     = (_Float16)((float)xv[u]     * sa[u]);
        o[u + 4] = (_Float16)((float)xv[u + 4] * sb[u]);
    }
    *(h8*)(xkt + (size_t)w * 64 + c0) = o;
}

// ---------------------------------------------------------------------------
// KB3: bilinear, zero-LDS. Block = 2 waves x 64 rows = 128 rows; wave does
// 4 row-tiles x 4 col-tiles; j-span 32 per blockIdx.y. All operands in
// registers: xa loaded once, tt per 8-j group (L1), B-frags streamed from L2
// with full-unroll pipelining. Epilogue: fire-and-forget f32 atomics.
// ---------------------------------------------------------------------------
__global__ __launch_bounds__(128, 3) void kb3_bilinear(const _Float16* __restrict__ xkt,
                                                       const _Float16* __restrict__ ttp,
                                                       const h8* __restrict__ wpack,
                                                       const int* __restrict__ idx_ji,
                                                       float* __restrict__ agg) {
    int tid = threadIdx.x;
    int lane = tid & 63, wv = tid >> 6;
    int qrow = lane & 15, quad = lane >> 4;
    int row0 = blockIdx.x * 128 + wv * 64;
    int jlo = blockIdx.y * 32;

    h8 xa[4][2];
#pragma unroll
    for (int rt = 0; rt < 4; ++rt) {
        const _Float16* rp = xkt + (size_t)(row0 + rt * 16 + qrow) * 64 + quad * 8;
        xa[rt][0] = *(const h8*)rp;
        xa[rt][1] = *(const h8*)(rp + 32);
    }

    f4 acc[4][4] = {};
#pragma unroll
    for (int jg = 0; jg < 4; ++jg) {
        h8 tg[4];
#pragma unroll
        for (int rt = 0; rt < 4; ++rt)
            tg[rt] = *(const h8*)(ttp + (size_t)(row0 + rt * 16 + qrow) * 64 + jlo + jg * 8);
#pragma unroll
        for (int ju = 0; ju < 8; ++ju) {
            int j = jlo + jg * 8 + ju;
            const h8* wj = wpack + (((size_t)j * 8) << 6) + lane;
            h8 b0[4], b1[4];
#pragma unroll
            for (int nt = 0; nt < 4; ++nt) {
                b0[nt] = wj[nt << 6];         // c=0
                b1[nt] = wj[(4 + nt) << 6];   // c=1
            }
#pragma unroll
            for (int rt = 0; rt < 4; ++rt) {
                _Float16 tv = tg[rt][ju];
                h8 t8 = {tv, tv, tv, tv, tv, tv, tv, tv};
                h8 a0 = xa[rt][0] * t8;
                h8 a1 = xa[rt][1] * t8;
#pragma unroll
                for (int nt = 0; nt < 4; ++nt) {
                    acc[rt][nt] = __builtin_amdgcn_mfma_f32_16x16x32_f16(a0, b0[nt], acc[rt][nt], 0, 0, 0);
                    acc[rt][nt] = __builtin_amdgcn_mfma_f32_16x16x32_f16(a1, b1[nt], acc[rt][nt], 0, 0, 0);
                }
            }
        }
    }

    // C/D layout: col = lane&15, row = quad*4 + reg  (verified m89/m91)
#pragma unroll
    for (int rt = 0; rt < 4; ++rt) {
#pragma unroll
        for (int rr = 0; rr < 4; ++rr) {
            int w = row0 + rt * 16 + quad * 4 + rr;
            int e = idx_ji[w];
            float* dst = agg + (size_t)e * 64 + qrow;
#pragma unroll
            for (int nt = 0; nt < 4; ++nt)
                atomicAdd(dst + nt * 16, acc[rt][nt][rr]);
        }
    }
}

// ---------------------------------------------------------------------------
// K4 (MFMA): out = swish( agg @ W_up ). K=64 (2 kt), N=256 (16 nt).
// Block 4 waves x 16 rows = 64 rows. No LDS.
// ---------------------------------------------------------------------------
__global__ __launch_bounds__(256) void k4_up(const float* __restrict__ agg,
                                             const h8* __restrict__ wpu,
                                             float* __restrict__ out) {
    int tid = threadIdx.x;
    int lane = tid & 63, wv = tid >> 6;
    int m = lane & 15, quad = lane >> 4;
    int rowb = blockIdx.x * 64 + wv * 16;

    f4 acc[16] = {};
#pragma unroll
    for (int kt = 0; kt < 2; ++kt) {
        const float* ap = agg + (size_t)(rowb + m) * 64 + kt * 32 + quad * 8;
        f4 alo = *(const f4*)ap;
        f4 ahi = *(const f4*)(ap + 4);
        h8 a;
#pragma unroll
        for (int u = 0; u < 4; ++u) {
            a[u]     = (_Float16)alo[u];
            a[u + 4] = (_Float16)ahi[u];
        }
#pragma unroll
        for (int nt = 0; nt < 16; ++nt) {
            h8 b = wpu[((kt * 16 + nt) << 6) + lane];
            acc[nt] = __builtin_amdgcn_mfma_f32_16x16x32_f16(a, b, acc[nt], 0, 0, 0);
        }
    }

#pragma unroll
    for (int nt = 0; nt < 16; ++nt)
#pragma unroll
        for (int rr = 0; rr < 4; ++rr) {
            int row = rowb + quad * 4 + rr;
            out[(size_t)row * 256 + nt * 16 + m] = swishf(acc[nt][rr]);
        }
}

// ---------------------------------------------------------------------------
extern "C" void kernel_launch(void* const* d_in, const int* in_sizes, int n_in,
                              void* d_out, int out_size, void* d_ws, size_t ws_size,
                              hipStream_t stream) {
    const float* rbf0   = (const float*)d_in[1];
    const float* sbf    = (const float*)d_in[2];
    const float* tin    = (const float*)d_in[3];
    const float* xkj    = (const float*)d_in[4];
    const int*   idx_kj = (const int*)d_in[6];
    const int*   idx_ji = (const int*)d_in[7];
    const float* W_rbf1 = (const float*)d_in[8];
    const float* W_rbf2 = (const float*)d_in[9];
    const float* W_sbf1 = (const float*)d_in[10];
    const float* W_sbf2 = (const float*)d_in[11];
    const float* W_t1   = (const float*)d_in[12];
    const float* W_down = (const float*)d_in[13];
    const float* W_up   = (const float*)d_in[14];
    const float* W_bil  = (const float*)d_in[15];

    // ws: xke 10.24MB | agg 20.48MB | wpack_bil 512KB | wpd 32KB | wpt 40KB | wpu 32KB
    char* ws = (char*)d_ws;
    _Float16* xke = (_Float16*)ws;
    float*    agg = (float*)(ws + 10240000);
    h8* wpack_bil = (h8*)(ws + 30720000);
    h8* wpd       = (h8*)(ws + 31244288);
    h8* wpt       = (h8*)(ws + 31277056);
    h8* wpu       = (h8*)(ws + 31318016);
    // tt/xkt live in d_out's first 20.5MB (dead before k4_up writes out)
    _Float16* ttb = (_Float16*)d_out;
    _Float16* xkt = (_Float16*)((char*)d_out + 10240000);
    float*    out = (float*)d_out;

    hipMemsetAsync(agg, 0, (size_t)E_N * 64 * 4, stream);
    kpack_all<<<154, 256, 0, stream>>>(W_bil, wpack_bil, W_down, wpd, W_t1, wpt, W_up, wpu);
    k1_down<<<625, 256, 0, stream>>>(rbf0, xkj, W_rbf1, W_rbf2, wpd, xke);
    kb1_tproj<<<625, 256, 0, stream>>>(tin, wpt, ttb);
    kb2_gather<<<2500, 256, 0, stream>>>(sbf, W_sbf1, W_sbf2, xke, idx_kj, xkt);
    kb3_bilinear<<<dim3(625, 2), 128, 0, stream>>>(xkt, ttb, wpack_bil, idx_ji, agg);
    k4_up<<<1250, 256, 0, stream>>>(agg, wpu, out);
}